// Round 10
// baseline (117.636 us; speedup 1.0000x reference)
//
#include <hip/hip_runtime.h>

typedef unsigned int  u32;
typedef unsigned short u16;

typedef float    f4  __attribute__((ext_vector_type(4)));
typedef short    bf8 __attribute__((ext_vector_type(8)));
typedef __fp16   h8  __attribute__((ext_vector_type(8)));
typedef __fp16   h2  __attribute__((ext_vector_type(2)));

#define NBLK   1280    // 5 blocks/CU resident (LDS <= 32 KB)
#define NCHUNK 4096    // 4096 chunks * 64 boards = 262144
#define ZSTR   104     // z1 row stride (u16); 52 dw/row spreads b128 starts over all 8 bank slots

// round-to-nearest-even fp32 -> bf16 bits
__device__ __forceinline__ u32 bfr(float f) {
    union { float f; u32 u; } v; v.f = f;
    return (v.u + 0x7fffu + ((v.u >> 16) & 1u)) >> 16;
}
__device__ __forceinline__ u32 pk2(float lo, float hi) { return bfr(lo) | (bfr(hi) << 16); }
__device__ __forceinline__ u32 pkh(float lo, float hi) {   // fp16 pair (RTZ, 1 inst)
    union { h2 h; u32 u; } v; v.h = __builtin_amdgcn_cvt_pkrtz(lo, hi); return v.u;
}
__device__ __forceinline__ u32 nrev(u32 x) {
    return ((x >> 12) & 0xFu) | ((x >> 4) & 0xF0u) | ((x << 4) & 0xF00u) | ((x << 12) & 0xF000u);
}

__launch_bounds__(256, 4)
__global__ void smartcnn_fused(const int* __restrict__ exps,
                               const float* __restrict__ c0w, const float* __restrict__ c0b,
                               const float* __restrict__ c1w,
                               const float* __restrict__ lw,  const float* __restrict__ lb,
                               const float* __restrict__ ow,  const float* __restrict__ ob,
                               float* __restrict__ out)
{
    __shared__ uint2  ThA[121];         // [v1*11+v2] -> 4 channels bf16 (relu(conv0 pair + bias))
    __shared__ uint2  TvA[121];         // [v1*11+v2] -> 4 channels bf16 (relu(conv1 pair))
    __shared__ u16    z1[64 * ZSTR];    // [G*16+m][k] bf16, k = 4*pos + channel (permuted K)
    __shared__ u32    zs[4][64 * 12];   // per-wave fp16 z2 staging for GEMM2 (48B/lane)
    __shared__ float4 Pbuf[4][4][16];   // [G][wave][m] logit partials
    __shared__ u32    flg[64];          // flip flags per board

    const int tid  = threadIdx.x;
    const int w    = tid >> 6;
    const int lane = tid & 63;
    const int m    = lane & 15;
    const int qd   = lane >> 4;

    // ---- packed-channel pair tables ----
    for (int i = tid; i < 121; i += 256) {
        int v1 = i / 11, v2 = i - v1 * 11;
        float hv[4], vv[4];
        #pragma unroll
        for (int c = 0; c < 4; ++c) {
            hv[c] = fmaxf(c0w[c*24 + 0] + c0w[c*24 + (1+v1)*2 + 0] + c0b[c]
                        + c0w[c*24 + 1] + c0w[c*24 + (1+v2)*2 + 1], 0.f);
            vv[c] = fmaxf(c1w[c*24 + 0] + c1w[c*24 + (1+v1)*2 + 0]
                        + c1w[c*24 + 1] + c1w[c*24 + (1+v2)*2 + 1], 0.f);
        }
        ThA[i] = make_uint2(pk2(hv[0], hv[1]), pk2(hv[2], hv[3]));
        TvA[i] = make_uint2(pk2(vv[0], vv[1]), pk2(vv[2], vv[3]));
    }

    // ---- W1 A-fragments (48 VGPR), K-permuted, staged through z1 (wave w's own rows) ----
    // FULLY UNROLLED over tt: af must be statically indexed or it demotes to scratch
    // (R8 post-mortem). Same-wave DS ops are in-order, so staging-read -> later
    // phase1-overwrite of the same z1 rows is WAR-safe without a barrier.
    bf8 af[4][3];
    {
        u16* srow = &z1[(w*16 + m) * ZSTR];
        #pragma unroll
        for (int tt = 0; tt < 4; ++tt) {
            const float* rowp = lw + (size_t)((w*4 + tt)*16 + m)*96 + qd*24;
            #pragma unroll
            for (int v = 0; v < 6; ++v) {
                float4 x = *(const float4*)(rowp + v*4);
                u16 e[4] = {(u16)bfr(x.x), (u16)bfr(x.y), (u16)bfr(x.z), (u16)bfr(x.w)};
                #pragma unroll
                for (int j = 0; j < 4; ++j) {
                    int ko = qd*24 + v*4 + j;
                    int kp = (ko < 48) ? ((ko % 12)*4 + ko/12)
                                       : (48 + ((ko - 48) % 12)*4 + (ko - 48)/12);
                    srow[kp] = e[j];
                }
            }
            #pragma unroll
            for (int s = 0; s < 3; ++s)
                af[tt][s] = *(const bf8*)(srow + s*32 + qd*8);
        }
    }
    // ---- out_w A-fragments, fp16 (8 VGPR): rows 0-3 = actions, rows 4-15 = 0 ----
    u32 owA[2][4];
    #pragma unroll
    for (int c = 0; c < 2; ++c) {
        int n8 = 64*w + 32*c + qd*8;
        #pragma unroll
        for (int k = 0; k < 4; ++k)
            owA[c][k] = (m < 4) ? pkh(ow[m*256 + n8 + 2*k], ow[m*256 + n8 + 2*k + 1]) : 0u;
    }
    // ---- linear_b as unpacked f4 (16 VGPR; saves 64 unpack VALU per wave-iter) ----
    f4 lb4[4];
    #pragma unroll
    for (int tt = 0; tt < 4; ++tt)
        lb4[tt] = *(const f4*)(lb + 64*w + 16*tt + qd*4);
    const float4 obv = *(const float4*)ob;

    __syncthreads();  // tables + af staging done before z1/zs reuse

    int bi = blockIdx.x;
    int4 e4 = *(const int4*)(exps + (size_t)(bi*64 + w*16 + m)*16 + qd*4);
    u32 fl = 0;       // flip flags for the pending epilogue
    int pb = -1;      // previous chunk's board base (pending epilogue), -1 = none

    #pragma unroll 1
    for (; bi < NCHUNK; bi += NBLK) {
        const int b0 = bi * 64;

        // ---- epilogue for previous chunk (reads Pbuf written before last barrier) ----
        if (pb >= 0) {
            float4 s0 = Pbuf[qd][0][m], s1 = Pbuf[qd][1][m];
            float4 s2 = Pbuf[qd][2][m], s3 = Pbuf[qd][3][m];
            float L0 = s0.x + s1.x + s2.x + s3.x + obv.x;
            float L1 = s0.y + s1.y + s2.y + s3.y + obv.y;
            float L2 = s0.z + s1.z + s2.z + s3.z + obv.z;
            float L3 = s0.w + s1.w + s2.w + s3.w + obv.w;
            float mx = fmaxf(fmaxf(L0, L1), fmaxf(L2, L3));
            float e0 = __expf(L0 - mx), e1 = __expf(L1 - mx), e2 = __expf(L2 - mx), e3 = __expf(L3 - mx);
            float inv = 1.0f / (e0 + e1 + e2 + e3);
            float p0 = e0 * inv, p1 = e1 * inv, p2 = e2 * inv, p3 = e3 * inv;
            float4 o;
            o.x = (fl & 1u) ? p1 : p0;
            o.y = (fl & 1u) ? p0 : p1;
            o.z = (fl & 2u) ? p3 : p2;
            o.w = (fl & 2u) ? p2 : p3;
            *(float4*)(out + (size_t)(pb + qd*16 + m) * 4) = o;
        }

        // ---- phase 1: build z1 + flg for this chunk's 64 boards ----
        {
            u32 pkd = (u32)e4.x | ((u32)e4.y << 4) | ((u32)e4.z << 8) | ((u32)e4.w << 12);
            u32 R0 = (u32)__shfl((int)pkd, m);
            u32 R1 = (u32)__shfl((int)pkd, m + 16);
            u32 R2 = (u32)__shfl((int)pkd, m + 32);
            u32 R3 = (u32)__shfl((int)pkd, m + 48);
            u32 c0v = R0 & 15u, c1v = (R0 >> 12) & 15u, c2v = R3 & 15u, c3v = (R3 >> 12) & 15u;
            u32 best = c0v; int ix = 0;
            if (c1v > best) { best = c1v; ix = 1; }
            if (c2v > best) { best = c2v; ix = 2; }
            if (c3v > best) { best = c3v; ix = 3; }
            const bool fv = (ix >= 2), fh = ((ix & 1) != 0);
            u32 F[4];
            F[0] = fv ? R3 : R0;
            F[1] = fv ? R2 : R1;
            F[2] = fv ? R1 : R2;
            F[3] = fv ? R0 : R3;
            #pragma unroll
            for (int i = 0; i < 4; ++i) F[i] = fh ? nrev(F[i]) : F[i];

            if (qd == 0) flg[w*16 + m] = (u32)fv | ((u32)fh << 1);

            // nibbles: row qd (for h) and column qd (for v)
            const u32 Fq = F[qd];
            u32 nbq[4], nbc[4];
            #pragma unroll
            for (int j = 0; j < 4; ++j) nbq[j] = (Fq >> (4*j)) & 15u;
            #pragma unroll
            for (int i = 0; i < 4; ++i) nbc[i] = (F[i] >> (4*qd)) & 15u;

            // 6 packed gathers: each uint2 = all 4 channels (bf16, relu'd)
            uint2 H0 = ThA[nbq[0]*11u + nbq[1]];
            uint2 H1 = ThA[nbq[1]*11u + nbq[2]];
            uint2 H2 = ThA[nbq[2]*11u + nbq[3]];
            uint2 V0 = TvA[nbc[0]*11u + nbc[1]];
            uint2 V1 = TvA[nbc[1]*11u + nbc[2]];
            uint2 V2 = TvA[nbc[2]*11u + nbc[3]];

            u16* zrow = &z1[(w*16 + m) * ZSTR];
            // h position p = qd*3 + j -> k = 4p + c; v position p = i*4 + qd -> k = 48 + 4p + c
            *(uint2*)(zrow + (qd*3 + 0)*4) = H0;
            *(uint2*)(zrow + (qd*3 + 1)*4) = H1;
            *(uint2*)(zrow + (qd*3 + 2)*4) = H2;
            *(uint2*)(zrow + 48 + (0*4 + qd)*4) = V0;
            *(uint2*)(zrow + 48 + (1*4 + qd)*4) = V1;
            *(uint2*)(zrow + 48 + (2*4 + qd)*4) = V2;
        }

        if (bi + NBLK < NCHUNK)
            e4 = *(const int4*)(exps + (size_t)((bi + NBLK)*64 + w*16 + m)*16 + qd*4);

        __syncthreads();  // sync_a: z1/flg ready; previous epilogue reads complete

        fl = flg[qd*16 + m];  // hoisted for NEXT epilogue (stable until next phase1)
        pb = b0;

        // ---- per board-group G: GEMM1 (bf16 MFMA) -> relu/fp16 -> GEMM2 (f16 MFMA) ----
        u32* zw = &zs[w][0];
        const int laneA = (((2*qd)    ) & 3)*16 + m;
        const int laneB = (((2*qd) + 1) & 3)*16 + m;
        #pragma unroll
        for (int G = 0; G < 4; ++G) {
            bf8 zb[3];
            #pragma unroll
            for (int s = 0; s < 3; ++s)
                zb[s] = *(const bf8*)(&z1[(G*16 + m)*ZSTR + s*32 + qd*8]);

            f4 acc_t[4] = {lb4[0], lb4[1], lb4[2], lb4[3]};
            #pragma unroll
            for (int s = 0; s < 3; ++s)
                #pragma unroll
                for (int tt = 0; tt < 4; ++tt)
                    acc_t[tt] = __builtin_amdgcn_mfma_f32_16x16x32_bf16(af[tt][s], zb[s], acc_t[tt], 0, 0, 0);

            // relu + fp16-pack this lane's 16 z2 values (features 64w+16tt+4qd+r, board (G,m))
            u32 z2p[8];
            #pragma unroll
            for (int tt = 0; tt < 4; ++tt) {
                z2p[tt*2+0] = pkh(fmaxf(acc_t[tt][0], 0.f), fmaxf(acc_t[tt][1], 0.f));
                z2p[tt*2+1] = pkh(fmaxf(acc_t[tt][2], 0.f), fmaxf(acc_t[tt][3], 0.f));
            }
            *(uint4*)&zw[lane*12 + 0] = make_uint4(z2p[0], z2p[1], z2p[2], z2p[3]);
            *(uint4*)&zw[lane*12 + 4] = make_uint4(z2p[4], z2p[5], z2p[6], z2p[7]);

            // B-fragment for GEMM2: lane (qd,m) needs k32 = 8qd+j of board m
            f4 acc2 = {0.f, 0.f, 0.f, 0.f};
            #pragma unroll
            for (int c = 0; c < 2; ++c) {
                const int tt = 2*c + (qd >> 1);
                uint2 uA = *(const uint2*)&zw[laneA*12 + tt*2];
                uint2 uB = *(const uint2*)&zw[laneB*12 + tt*2];
                union { u32 u[4]; h8 v; } bu, au;
                bu.u[0] = uA.x; bu.u[1] = uA.y; bu.u[2] = uB.x; bu.u[3] = uB.y;
                au.u[0] = owA[c][0]; au.u[1] = owA[c][1]; au.u[2] = owA[c][2]; au.u[3] = owA[c][3];
                acc2 = __builtin_amdgcn_mfma_f32_16x16x32_f16(au.v, bu.v, acc2, 0, 0, 0);
            }
            // D rows 0-3 (= actions) live in qd==0 lanes, col = board m
            if (qd == 0)
                Pbuf[G][w][m] = make_float4(acc2[0], acc2[1], acc2[2], acc2[3]);
        }
        __syncthreads();  // sync_b: Pbuf complete; z1/zs safe to overwrite next chunk
    }

    // ---- final epilogue (last processed chunk) ----
    if (pb >= 0) {
        float4 s0 = Pbuf[qd][0][m], s1 = Pbuf[qd][1][m];
        float4 s2 = Pbuf[qd][2][m], s3 = Pbuf[qd][3][m];
        float L0 = s0.x + s1.x + s2.x + s3.x + obv.x;
        float L1 = s0.y + s1.y + s2.y + s3.y + obv.y;
        float L2 = s0.z + s1.z + s2.z + s3.z + obv.z;
        float L3 = s0.w + s1.w + s2.w + s3.w + obv.w;
        float mx = fmaxf(fmaxf(L0, L1), fmaxf(L2, L3));
        float e0 = __expf(L0 - mx), e1 = __expf(L1 - mx), e2 = __expf(L2 - mx), e3 = __expf(L3 - mx);
        float inv = 1.0f / (e0 + e1 + e2 + e3);
        float p0 = e0 * inv, p1 = e1 * inv, p2 = e2 * inv, p3 = e3 * inv;
        float4 o;
        o.x = (fl & 1u) ? p1 : p0;
        o.y = (fl & 1u) ? p0 : p1;
        o.z = (fl & 2u) ? p3 : p2;
        o.w = (fl & 2u) ? p2 : p3;
        *(float4*)(out + (size_t)(pb + qd*16 + m) * 4) = o;
    }
}

extern "C" void kernel_launch(void* const* d_in, const int* in_sizes, int n_in,
                              void* d_out, int out_size, void* d_ws, size_t ws_size,
                              hipStream_t stream) {
    const int*   exps = (const int*)  d_in[0];
    const float* c0w  = (const float*)d_in[1];
    const float* c0b  = (const float*)d_in[2];
    const float* c1w  = (const float*)d_in[3];
    const float* lw   = (const float*)d_in[4];
    const float* lbv  = (const float*)d_in[5];
    const float* oww  = (const float*)d_in[6];
    const float* obv  = (const float*)d_in[7];
    smartcnn_fused<<<NBLK, 256, 0, stream>>>(exps, c0w, c0b, c1w, lw, lbv, oww, obv, (float*)d_out);
}

// Round 11
// 104.034 us; speedup vs baseline: 1.1307x; 1.1307x over previous
//
#include <hip/hip_runtime.h>

typedef unsigned int  u32;
typedef unsigned short u16;

typedef float    f4  __attribute__((ext_vector_type(4)));
typedef short    bf8 __attribute__((ext_vector_type(8)));
typedef __fp16   h8  __attribute__((ext_vector_type(8)));
typedef __fp16   h2  __attribute__((ext_vector_type(2)));

#define NBLK  1024
#define ITERS 4      // 1024 * 4 * 64 = 262144 boards
#define ZSTR  104    // z1 row stride (u16); 52 dw/row spreads b128 starts over all 8 bank slots

// round-to-nearest-even fp32 -> bf16 bits
__device__ __forceinline__ u32 bfr(float f) {
    union { float f; u32 u; } v; v.f = f;
    return (v.u + 0x7fffu + ((v.u >> 16) & 1u)) >> 16;
}
__device__ __forceinline__ u32 pk2(float lo, float hi) { return bfr(lo) | (bfr(hi) << 16); }
__device__ __forceinline__ u32 pkh(float lo, float hi) {   // fp16 pair (RTZ, 1 inst)
    union { h2 h; u32 u; } v; v.h = __builtin_amdgcn_cvt_pkrtz(lo, hi); return v.u;
}
__device__ __forceinline__ u32 nrev(u32 x) {
    return ((x >> 12) & 0xFu) | ((x >> 4) & 0xF0u) | ((x << 4) & 0xF00u) | ((x << 12) & 0xF000u);
}

__launch_bounds__(256, 4)
__global__ void smartcnn_fused(const int* __restrict__ exps,
                               const float* __restrict__ c0w, const float* __restrict__ c0b,
                               const float* __restrict__ c1w,
                               const float* __restrict__ lw,  const float* __restrict__ lb,
                               const float* __restrict__ ow,  const float* __restrict__ ob,
                               float* __restrict__ out)
{
    __shared__ uint2  ThA[121];         // [v1*11+v2] -> 4 channels bf16 (relu(conv0 pair + bias))
    __shared__ uint2  TvA[121];         // [v1*11+v2] -> 4 channels bf16 (relu(conv1 pair))
    __shared__ u16    z1[64 * ZSTR];    // [G*16+m][k] bf16, k = 4*pos + channel (permuted K)
    __shared__ float4 Pbuf[4][4][16];   // [G][wave][m] logit partials
    __shared__ u32    flg[64];          // flip flags per board

    const int tid  = threadIdx.x;
    const int w    = tid >> 6;
    const int lane = tid & 63;
    const int m    = lane & 15;
    const int qd   = lane >> 4;

    // Feature permutation across GEMM1 M-tiles: tile tt, tile-row i=4q+r holds
    // feature base(tt)+8q+r  (base = 0,4,32,36). Then lane (qd,m)'s accumulator
    // rows are exactly the GEMM2 B-frag features 32c+8qd+j -> no staging needed.
    // lw rows and lb follow this permutation; ow stays canonical.

    // ---- packed-channel pair tables ----
    for (int i = tid; i < 121; i += 256) {
        int v1 = i / 11, v2 = i - v1 * 11;
        float hv[4], vv[4];
        #pragma unroll
        for (int c = 0; c < 4; ++c) {
            hv[c] = fmaxf(c0w[c*24 + 0] + c0w[c*24 + (1+v1)*2 + 0] + c0b[c]
                        + c0w[c*24 + 1] + c0w[c*24 + (1+v2)*2 + 1], 0.f);
            vv[c] = fmaxf(c1w[c*24 + 0] + c1w[c*24 + (1+v1)*2 + 0]
                        + c1w[c*24 + 1] + c1w[c*24 + (1+v2)*2 + 1], 0.f);
        }
        ThA[i] = make_uint2(pk2(hv[0], hv[1]), pk2(hv[2], hv[3]));
        TvA[i] = make_uint2(pk2(vv[0], vv[1]), pk2(vv[2], vv[3]));
    }

    // ---- W1 A-fragments (48 VGPR), K-permuted, M-permuted, staged through z1 ----
    // FULLY UNROLLED over tt: af must be statically indexed or it demotes to scratch
    // (R8 post-mortem). Same-wave DS ops are in-order => WAR-safe reuse of z1 rows.
    bf8 af[4][3];
    {
        u16* srow = &z1[(w*16 + m) * ZSTR];
        #pragma unroll
        for (int tt = 0; tt < 4; ++tt) {
            const int tbase = ((tt & 1) ? 4 : 0) + ((tt >> 1) ? 32 : 0);
            const int fid = 64*w + tbase + 8*(m >> 2) + (m & 3);   // M-permuted feature row
            const float* rowp = lw + (size_t)fid*96 + qd*24;
            #pragma unroll
            for (int v = 0; v < 6; ++v) {
                float4 x = *(const float4*)(rowp + v*4);
                u16 e[4] = {(u16)bfr(x.x), (u16)bfr(x.y), (u16)bfr(x.z), (u16)bfr(x.w)};
                #pragma unroll
                for (int j = 0; j < 4; ++j) {
                    int ko = qd*24 + v*4 + j;
                    int kp = (ko < 48) ? ((ko % 12)*4 + ko/12)
                                       : (48 + ((ko - 48) % 12)*4 + (ko - 48)/12);
                    srow[kp] = e[j];
                }
            }
            #pragma unroll
            for (int s = 0; s < 3; ++s)
                af[tt][s] = *(const bf8*)(srow + s*32 + qd*8);
        }
    }
    // ---- out_w A-fragments, fp16 (8 VGPR): rows 0-3 = actions, rows 4-15 = 0 ----
    u32 owA[2][4];
    #pragma unroll
    for (int c = 0; c < 2; ++c) {
        int n8 = 64*w + 32*c + qd*8;
        #pragma unroll
        for (int k = 0; k < 4; ++k)
            owA[c][k] = (m < 4) ? pkh(ow[m*256 + n8 + 2*k], ow[m*256 + n8 + 2*k + 1]) : 0u;
    }
    // ---- linear_b as f4, M-permuted: lb4[tt][r] = lb[64w + tbase(tt) + 8qd + r] ----
    f4 lb4[4];
    #pragma unroll
    for (int tt = 0; tt < 4; ++tt) {
        const int tbase = ((tt & 1) ? 4 : 0) + ((tt >> 1) ? 32 : 0);
        lb4[tt] = *(const f4*)(lb + 64*w + tbase + 8*qd);
    }
    const float4 obv = *(const float4*)ob;

    const int b0 = blockIdx.x * (ITERS * 64);
    __syncthreads();  // tables + af staging done before z1 reuse

    int4 e4 = *(const int4*)(exps + (size_t)(b0 + w*16 + m)*16 + qd*4);
    u32 fl = 0;  // flip flags for the pending epilogue, carried in-register

    #pragma unroll 1
    for (int it = 0; it < ITERS; ++it) {
        // ---- epilogue for iteration it-1 (reads Pbuf written before last barrier) ----
        if (it > 0) {
            float4 s0 = Pbuf[qd][0][m], s1 = Pbuf[qd][1][m];
            float4 s2 = Pbuf[qd][2][m], s3 = Pbuf[qd][3][m];
            float L0 = s0.x + s1.x + s2.x + s3.x + obv.x;
            float L1 = s0.y + s1.y + s2.y + s3.y + obv.y;
            float L2 = s0.z + s1.z + s2.z + s3.z + obv.z;
            float L3 = s0.w + s1.w + s2.w + s3.w + obv.w;
            float mx = fmaxf(fmaxf(L0, L1), fmaxf(L2, L3));
            float e0 = __expf(L0 - mx), e1 = __expf(L1 - mx), e2 = __expf(L2 - mx), e3 = __expf(L3 - mx);
            float inv = 1.0f / (e0 + e1 + e2 + e3);
            float p0 = e0 * inv, p1 = e1 * inv, p2 = e2 * inv, p3 = e3 * inv;
            float4 o;
            o.x = (fl & 1u) ? p1 : p0;
            o.y = (fl & 1u) ? p0 : p1;
            o.z = (fl & 2u) ? p3 : p2;
            o.w = (fl & 2u) ? p2 : p3;
            *(float4*)(out + (size_t)(b0 + (it-1)*64 + qd*16 + m) * 4) = o;
        }

        // ---- phase 1: build z1 + flg for this iteration's 64 boards ----
        {
            u32 pkd = (u32)e4.x | ((u32)e4.y << 4) | ((u32)e4.z << 8) | ((u32)e4.w << 12);
            u32 R0 = (u32)__shfl((int)pkd, m);
            u32 R1 = (u32)__shfl((int)pkd, m + 16);
            u32 R2 = (u32)__shfl((int)pkd, m + 32);
            u32 R3 = (u32)__shfl((int)pkd, m + 48);
            u32 c0v = R0 & 15u, c1v = (R0 >> 12) & 15u, c2v = R3 & 15u, c3v = (R3 >> 12) & 15u;
            u32 best = c0v; int ix = 0;
            if (c1v > best) { best = c1v; ix = 1; }
            if (c2v > best) { best = c2v; ix = 2; }
            if (c3v > best) { best = c3v; ix = 3; }
            const bool fv = (ix >= 2), fh = ((ix & 1) != 0);
            u32 F[4];
            F[0] = fv ? R3 : R0;
            F[1] = fv ? R2 : R1;
            F[2] = fv ? R1 : R2;
            F[3] = fv ? R0 : R3;
            #pragma unroll
            for (int i = 0; i < 4; ++i) F[i] = fh ? nrev(F[i]) : F[i];

            if (qd == 0) flg[w*16 + m] = (u32)fv | ((u32)fh << 1);

            // nibbles: row qd (for h) and column qd (for v)
            const u32 Fq = F[qd];
            u32 nbq[4], nbc[4];
            #pragma unroll
            for (int j = 0; j < 4; ++j) nbq[j] = (Fq >> (4*j)) & 15u;
            #pragma unroll
            for (int i = 0; i < 4; ++i) nbc[i] = (F[i] >> (4*qd)) & 15u;

            // 6 packed gathers: each uint2 = all 4 channels (bf16, relu'd)
            uint2 H0 = ThA[nbq[0]*11u + nbq[1]];
            uint2 H1 = ThA[nbq[1]*11u + nbq[2]];
            uint2 H2 = ThA[nbq[2]*11u + nbq[3]];
            uint2 V0 = TvA[nbc[0]*11u + nbc[1]];
            uint2 V1 = TvA[nbc[1]*11u + nbc[2]];
            uint2 V2 = TvA[nbc[2]*11u + nbc[3]];

            u16* zrow = &z1[(w*16 + m) * ZSTR];
            // h position p = qd*3 + j -> k = 4p + c; v position p = i*4 + qd -> k = 48 + 4p + c
            *(uint2*)(zrow + (qd*3 + 0)*4) = H0;
            *(uint2*)(zrow + (qd*3 + 1)*4) = H1;
            *(uint2*)(zrow + (qd*3 + 2)*4) = H2;
            *(uint2*)(zrow + 48 + (0*4 + qd)*4) = V0;
            *(uint2*)(zrow + 48 + (1*4 + qd)*4) = V1;
            *(uint2*)(zrow + 48 + (2*4 + qd)*4) = V2;
        }

        if (it + 1 < ITERS)
            e4 = *(const int4*)(exps + (size_t)(b0 + (it+1)*64 + w*16 + m)*16 + qd*4);

        __syncthreads();  // sync_a: z1/flg ready; previous epilogue reads complete

        fl = flg[qd*16 + m];  // hoisted for NEXT epilogue (stable until next phase1)

        // ---- per board-group G: GEMM1 (bf16 MFMA) -> relu/fp16 in-lane -> GEMM2 (f16 MFMA) ----
        #pragma unroll
        for (int G = 0; G < 4; ++G) {
            bf8 zb[3];
            #pragma unroll
            for (int s = 0; s < 3; ++s)
                zb[s] = *(const bf8*)(&z1[(G*16 + m)*ZSTR + s*32 + qd*8]);

            f4 acc_t[4] = {lb4[0], lb4[1], lb4[2], lb4[3]};
            #pragma unroll
            for (int s = 0; s < 3; ++s)
                #pragma unroll
                for (int tt = 0; tt < 4; ++tt)
                    acc_t[tt] = __builtin_amdgcn_mfma_f32_16x16x32_bf16(af[tt][s], zb[s], acc_t[tt], 0, 0, 0);

            // M-permutation makes lane (qd,m)'s acc rows = features 32c+8qd+j of board m:
            // B-frag for GEMM2 chunk c is relu+pack of acc_t[2c],acc_t[2c+1] -- in-lane.
            f4 acc2 = {0.f, 0.f, 0.f, 0.f};
            #pragma unroll
            for (int c = 0; c < 2; ++c) {
                union { u32 u[4]; h8 v; } bu, au;
                bu.u[0] = pkh(fmaxf(acc_t[2*c  ][0], 0.f), fmaxf(acc_t[2*c  ][1], 0.f));
                bu.u[1] = pkh(fmaxf(acc_t[2*c  ][2], 0.f), fmaxf(acc_t[2*c  ][3], 0.f));
                bu.u[2] = pkh(fmaxf(acc_t[2*c+1][0], 0.f), fmaxf(acc_t[2*c+1][1], 0.f));
                bu.u[3] = pkh(fmaxf(acc_t[2*c+1][2], 0.f), fmaxf(acc_t[2*c+1][3], 0.f));
                au.u[0] = owA[c][0]; au.u[1] = owA[c][1]; au.u[2] = owA[c][2]; au.u[3] = owA[c][3];
                acc2 = __builtin_amdgcn_mfma_f32_16x16x32_f16(au.v, bu.v, acc2, 0, 0, 0);
            }
            // D rows 0-3 (= actions) live in qd==0 lanes, col = board m
            if (qd == 0)
                Pbuf[G][w][m] = make_float4(acc2[0], acc2[1], acc2[2], acc2[3]);
        }
        __syncthreads();  // sync_b: Pbuf complete; z1 safe to overwrite next iter
    }

    // ---- final epilogue (it = ITERS-1) ----
    {
        float4 s0 = Pbuf[qd][0][m], s1 = Pbuf[qd][1][m];
        float4 s2 = Pbuf[qd][2][m], s3 = Pbuf[qd][3][m];
        float L0 = s0.x + s1.x + s2.x + s3.x + obv.x;
        float L1 = s0.y + s1.y + s2.y + s3.y + obv.y;
        float L2 = s0.z + s1.z + s2.z + s3.z + obv.z;
        float L3 = s0.w + s1.w + s2.w + s3.w + obv.w;
        float mx = fmaxf(fmaxf(L0, L1), fmaxf(L2, L3));
        float e0 = __expf(L0 - mx), e1 = __expf(L1 - mx), e2 = __expf(L2 - mx), e3 = __expf(L3 - mx);
        float inv = 1.0f / (e0 + e1 + e2 + e3);
        float p0 = e0 * inv, p1 = e1 * inv, p2 = e2 * inv, p3 = e3 * inv;
        float4 o;
        o.x = (fl & 1u) ? p1 : p0;
        o.y = (fl & 1u) ? p0 : p1;
        o.z = (fl & 2u) ? p3 : p2;
        o.w = (fl & 2u) ? p2 : p3;
        *(float4*)(out + (size_t)(b0 + (ITERS-1)*64 + qd*16 + m) * 4) = o;
    }
}

extern "C" void kernel_launch(void* const* d_in, const int* in_sizes, int n_in,
                              void* d_out, int out_size, void* d_ws, size_t ws_size,
                              hipStream_t stream) {
    const int*   exps = (const int*)  d_in[0];
    const float* c0w  = (const float*)d_in[1];
    const float* c0b  = (const float*)d_in[2];
    const float* c1w  = (const float*)d_in[3];
    const float* lw   = (const float*)d_in[4];
    const float* lbv  = (const float*)d_in[5];
    const float* oww  = (const float*)d_in[6];
    const float* obv  = (const float*)d_in[7];
    smartcnn_fused<<<NBLK, 256, 0, stream>>>(exps, c0w, c0b, c1w, lw, lbv, oww, obv, (float*)d_out);
}